// Round 4
// baseline (594.042 us; speedup 1.0000x reference)
//
#include <hip/hip_runtime.h>
#include <math.h>

#define Bb 64
#define Nn 8192
#define MWw 128
#define Hh 8
#define Cc 1024
#define HDd 128
#define Kk 3

__device__ __forceinline__ float dot4(float4 a, float4 b) {
  return a.x*b.x + a.y*b.y + a.z*b.z + a.w*b.w;
}
__device__ __forceinline__ float sigmoidf_(float x) { return 1.0f / (1.0f + __expf(-x)); }
__device__ __forceinline__ float softplusf_(float x) {
  return fmaxf(x, 0.0f) + log1pf(__expf(-fabsf(x)));
}

// Hand-rolled grid barrier (graph-capture-safe; no cooperative launch).
// Leader: release-fence, agent-scope arrive, acquire-spin with bailout.
__device__ __forceinline__ void grid_barrier(unsigned* bar, unsigned target) {
  __syncthreads();
  if (threadIdx.x == 0) {
    __threadfence();   // agent release: drain + L2 writeback (cross-XCD)
    __hip_atomic_fetch_add(bar, 1u, __ATOMIC_ACQ_REL, __HIP_MEMORY_SCOPE_AGENT);
    int spins = 0;
    while (__hip_atomic_load(bar, __ATOMIC_ACQUIRE, __HIP_MEMORY_SCOPE_AGENT) < target) {
      __builtin_amdgcn_s_sleep(8);
      if (++spins > (1 << 22)) break;   // ~1s bailout: wrong-answer > hang
    }
    __threadfence();   // agent acquire: invalidate stale L1/L2
  }
  __syncthreads();
}

// ---------------------------------------------------------------------------
// K1: one block per (b,h), 1024 threads. Block 0 zeroes Z/S/barriers/out.
// ---------------------------------------------------------------------------
__global__ __launch_bounds__(1024) void k_params(
    const float* __restrict__ cs, const float* __restrict__ W_head, const float* __restrict__ b_head,
    const float* __restrict__ W_reset, const float* __restrict__ b_reset,
    const float* __restrict__ W_key, const float* __restrict__ b_key,
    const float* __restrict__ W_beta, const float* __restrict__ b_beta,
    const float* __restrict__ W_gate, const float* __restrict__ b_gate,
    const float* __restrict__ W_shift, const float* __restrict__ b_shift,
    const float* __restrict__ W_gamma, const float* __restrict__ b_gamma,
    float* __restrict__ key_ws, float* __restrict__ params,
    float* __restrict__ zs, float* __restrict__ outp)
{
  int bh = blockIdx.x;
  int b = bh >> 3, h = bh & 7;
  int t = threadIdx.x;
  int d = t & 127, sl = t >> 7;   // 8 slices
  __shared__ float red[8][128];
  __shared__ float head_s[128];
  __shared__ float key_s[128];
  __shared__ float wred[16];

  if (bh == 0) {
    // zero Z (512) + S (512) + barrier counters (16) and out accumulator
    zs[t] = 0.0f;
    if (t < 16) zs[1024 + t] = 0.0f;
    #pragma unroll
    for (int j = 0; j < 8; ++j) outp[j * 1024 + t] = 0.0f;
  }

  const float* csb = cs + b * Cc + sl * 128;
  const float* w0 = W_head + (size_t)(sl * 128) * (Hh * HDd) + h * HDd + d;
  float acc = 0.0f;
  #pragma unroll 8
  for (int c = 0; c < 128; ++c) acc = fmaf(csb[c], w0[(size_t)c * (Hh * HDd)], acc);
  red[sl][d] = acc;
  __syncthreads();
  if (t < 128) {
    float s = b_head[h * HDd + t];
    #pragma unroll
    for (int j = 0; j < 8; ++j) s += red[j][t];
    head_s[t] = s;
  }
  __syncthreads();

  {
    const float* wk = W_key + (size_t)h * HDd * MWw + (sl * 16) * MWw + d;
    float ka = 0.0f;
    #pragma unroll
    for (int dd = 0; dd < 16; ++dd) ka = fmaf(head_s[sl * 16 + dd], wk[dd * MWw], ka);
    red[sl][d] = ka;
  }
  __syncthreads();
  if (t < 128) {
    float kv = b_key[h * MWw + t];
    #pragma unroll
    for (int j = 0; j < 8; ++j) kv += red[j][t];
    key_ws[bh * MWw + t] = kv;
    key_s[t] = kv;
  }
  __syncthreads();

  float hd = head_s[d];
  float v;
  switch (sl) {
    case 0: v = hd * W_reset[h * HDd + d]; break;
    case 1: v = hd * W_beta[h * HDd + d]; break;
    case 2: v = hd * W_gate[h * HDd + d]; break;
    case 3: v = hd * W_gamma[h * HDd + d]; break;
    case 4: v = hd * W_shift[(h * HDd + d) * Kk + 0]; break;
    case 5: v = hd * W_shift[(h * HDd + d) * Kk + 1]; break;
    case 6: v = hd * W_shift[(h * HDd + d) * Kk + 2]; break;
    default: v = key_s[d] * key_s[d]; break;
  }
  v += __shfl_xor(v, 1, 64);
  v += __shfl_xor(v, 2, 64);
  v += __shfl_xor(v, 4, 64);
  v += __shfl_xor(v, 8, 64);
  v += __shfl_xor(v, 16, 64);
  v += __shfl_xor(v, 32, 64);
  if ((t & 63) == 0) wred[t >> 6] = v;
  __syncthreads();
  if (t == 0) {
    float r0 = wred[0]  + wred[1];
    float r1 = wred[2]  + wred[3];
    float r2 = wred[4]  + wred[5];
    float r3 = wred[6]  + wred[7];
    float r4 = wred[8]  + wred[9];
    float r5 = wred[10] + wred[11];
    float r6 = wred[12] + wred[13];
    float r7 = wred[14] + wred[15];
    float reset = sigmoidf_(r0 + b_reset[h]);
    float beta  = softplusf_(r1 + b_beta[h]);
    float gate  = sigmoidf_(r2 + b_gate[h]);
    float gamma = 1.0f + softplusf_(r3 + b_gamma[h]);
    float a0 = r4 + b_shift[h * Kk + 0];
    float a1 = r5 + b_shift[h * Kk + 1];
    float a2 = r6 + b_shift[h * Kk + 2];
    float mx = fmaxf(a0, fmaxf(a1, a2));
    float e0 = __expf(a0 - mx), e1 = __expf(a1 - mx), e2 = __expf(a2 - mx);
    float inv = 1.0f / (e0 + e1 + e2);
    float* P = params + bh * 8;
    P[0] = reset; P[1] = beta; P[2] = gate; P[3] = gamma;
    P[4] = e0 * inv; P[5] = e1 * inv; P[6] = e2 * inv;
    P[7] = sqrtf(r7);
  }
}

// ---------------------------------------------------------------------------
// K2fused: grid 8x64 = 512 blocks x 256 thr, 2 blocks/CU = exactly resident
// (LDS 46KB x2 = 92 <= 160KB; VGPR capped 256 by launch_bounds). Each block
// owns rows [c*1024, c*1024+1024) of batch b for ALL 8 heads. e -> w_g ->
// w_pow live in ONE 33KB LDS buffer across two grid barriers; the e_ws / wp
// HBM round-trips (~67MB) vanish. Cross-block scalars (Z, S, e-halos) move
// via agent-scope atomics (immune to per-XCD L2 staleness).
//   Phase A: sim -> e in LDS, Z atomics, halo export.   [barrier 0]
//   Phase B: w_g in place, circular conv + pow, S atomics. [barrier 1]
//   Phase C: normalize -> write new_w, merged coef, read pass -> out atomics.
// ---------------------------------------------------------------------------
#define ESTRIDE 1032   // +8 floats: head rows offset by 8 banks -> 2-way, free

__global__ __launch_bounds__(256, 2) void k_fused(
    const float* __restrict__ mem, const float* __restrict__ key_ws,
    const float* __restrict__ params, const float* __restrict__ prev,
    const float* __restrict__ defw, const float* __restrict__ merge_w,
    float* __restrict__ Z, float* __restrict__ S, float* __restrict__ eh,
    unsigned* __restrict__ bar, float* __restrict__ neww, float* __restrict__ out)
{
  int c = blockIdx.x, b = blockIdx.y;
  int t = threadIdx.x;
  int lane = t & 63, wid = t >> 6;
  int sub = lane & 7, rid = lane >> 3;
  int n0 = c * 1024;

  __shared__ float4 keys[8][32];
  __shared__ float betas[8], knorms[8];
  __shared__ float e_s[8 * ESTRIDE];   // e -> w_g -> w_pow, 33 KB
  __shared__ float pL[64];
  __shared__ float zL[8];
  __shared__ float wgh[2][8];          // w_g halos [side][h]
  __shared__ float kh_s[8], invS_s[8];
  __shared__ float coef_s[1024];
  __shared__ float4 red4[256];

  // ---------------- Phase A: content sim, e, Z ----------------
  if (t < 8) { betas[t] = params[(b * 8 + t) * 8 + 1]; knorms[t] = params[(b * 8 + t) * 8 + 7]; }
  { int h = t >> 5, q = t & 31;
    keys[h][q] = ((const float4*)key_ws)[(b * 8 + h) * 32 + q]; }
  __syncthreads();

  float4 kreg[8][4];
  #pragma unroll
  for (int h2 = 0; h2 < 8; ++h2) {
    kreg[h2][0] = keys[h2][sub];
    kreg[h2][1] = keys[h2][sub + 8];
    kreg[h2][2] = keys[h2][sub + 16];
    kreg[h2][3] = keys[h2][sub + 24];
  }

  const float4* m4 = (const float4*)mem + (size_t)b * Nn * 32;
  float beta = betas[sub], kn = knorms[sub];
  float zloc = 0.0f;

  #pragma unroll 1
  for (int itr = 0; itr < 16; ++itr) {
    int nl = itr * 64 + wid * 16 + rid;   // local row for r=0; r adds 8
    float4 m[2][4];
    float nrm[2];
    float acc[2][8];
    #pragma unroll
    for (int r = 0; r < 2; ++r) {
      const float4* rp = m4 + (size_t)(n0 + nl + r * 8) * 32 + sub;
      m[r][0] = rp[0]; m[r][1] = rp[8]; m[r][2] = rp[16]; m[r][3] = rp[24];
    }
    #pragma unroll
    for (int r = 0; r < 2; ++r) {
      nrm[r] = dot4(m[r][0], m[r][0]) + dot4(m[r][1], m[r][1])
             + dot4(m[r][2], m[r][2]) + dot4(m[r][3], m[r][3]);
      #pragma unroll
      for (int h2 = 0; h2 < 8; ++h2) {
        acc[r][h2] = dot4(m[r][0], kreg[h2][0]) + dot4(m[r][1], kreg[h2][1])
                   + dot4(m[r][2], kreg[h2][2]) + dot4(m[r][3], kreg[h2][3]);
      }
    }
    #pragma unroll
    for (int r = 0; r < 2; ++r) {
      float* a = acc[r];
      bool h1 = (sub & 1) != 0;
      float v40 = (h1 ? a[1] : a[0]) + __shfl_xor(h1 ? a[0] : a[1], 1, 64);
      float v41 = (h1 ? a[3] : a[2]) + __shfl_xor(h1 ? a[2] : a[3], 1, 64);
      float v42 = (h1 ? a[5] : a[4]) + __shfl_xor(h1 ? a[4] : a[5], 1, 64);
      float v43 = (h1 ? a[7] : a[6]) + __shfl_xor(h1 ? a[6] : a[7], 1, 64);
      bool h2b = (sub & 2) != 0;
      float v20 = (h2b ? v41 : v40) + __shfl_xor(h2b ? v40 : v41, 2, 64);
      float v21 = (h2b ? v43 : v42) + __shfl_xor(h2b ? v42 : v43, 2, 64);
      bool h4 = (sub & 4) != 0;
      float dsum = (h4 ? v21 : v20) + __shfl_xor(h4 ? v20 : v21, 4, 64);
      float nr = nrm[r];
      nr += __shfl_xor(nr, 1, 64);
      nr += __shfl_xor(nr, 2, 64);
      nr += __shfl_xor(nr, 4, 64);
      float s = beta * dsum / (kn * sqrtf(nr) + 1e-8f);
      float e = __expf(s - beta);
      e_s[sub * ESTRIDE + nl + r * 8] = e;
      zloc += e;
    }
  }
  zloc += __shfl_xor(zloc, 8, 64);
  zloc += __shfl_xor(zloc, 16, 64);
  zloc += __shfl_xor(zloc, 32, 64);
  if (lane < 8) atomicAdd(&Z[b * 8 + lane], zloc);
  __syncthreads();
  // halo export [b][c][side][h] via agent-scope stores
  if (t < 16) {
    int hh = t & 7, side = t >> 3;
    __hip_atomic_store(&eh[(b * 8 + c) * 16 + side * 8 + hh],
                       e_s[hh * ESTRIDE + (side ? 1023 : 0)],
                       __ATOMIC_RELAXED, __HIP_MEMORY_SCOPE_AGENT);
  }
  grid_barrier(&bar[0], 512u);

  // ---------------- Phase B: w_g, circular conv, pow, S ----------------
  if (t < 64) pL[t] = params[b * 64 + t];
  if (t < 8)
    zL[t] = __hip_atomic_load(&Z[b * 8 + t], __ATOMIC_RELAXED, __HIP_MEMORY_SCOPE_AGENT);
  __syncthreads();

  int h = t >> 5, q = t & 31;
  float reset = pL[h * 8 + 0], gate = pL[h * 8 + 2], gamma = pL[h * 8 + 3];
  float s0 = pL[h * 8 + 4], s1 = pL[h * 8 + 5], s2 = pL[h * 8 + 6];
  float invZg = gate / zL[h];
  float om = 1.0f - gate, omr = 1.0f - reset;
  size_t gbase = (size_t)(b * 8 + h) * Nn + n0;
  const float4* p4 = (const float4*)(prev + gbase);
  const float4* d4 = (const float4*)(defw + gbase);
  float* wgp = &e_s[h * ESTRIDE];

  #pragma unroll
  for (int k = 0; k < 8; ++k) {
    int q4 = q + 32 * k;
    float4 e4 = *(const float4*)&wgp[q4 * 4];
    float4 pv = p4[q4], dv = d4[q4];
    float4 w;
    w.x = invZg * e4.x + om * (pv.x * omr + dv.x * reset);
    w.y = invZg * e4.y + om * (pv.y * omr + dv.y * reset);
    w.z = invZg * e4.z + om * (pv.z * omr + dv.z * reset);
    w.w = invZg * e4.w + om * (pv.w * omr + dv.w * reset);
    *(float4*)&wgp[q4 * 4] = w;
  }
  // halo w_g: side0 = row n0-1 (right edge of block c-1), side1 = n0+1024
  if (t < 16) {
    int hh = t & 7, side = t >> 3;
    int nbr = side ? ((c + 1) & 7) : ((c + 7) & 7);
    float e = __hip_atomic_load(&eh[(b * 8 + nbr) * 16 + (side ? 0 : 8) + hh],
                                __ATOMIC_RELAXED, __HIP_MEMORY_SCOPE_AGENT);
    int hrow = side ? ((n0 + 1024) & (Nn - 1)) : ((n0 + Nn - 1) & (Nn - 1));
    float rst = pL[hh * 8 + 0], gt = pL[hh * 8 + 2];
    float iZg = gt / zL[hh];
    size_t gi = (size_t)(b * 8 + hh) * Nn + hrow;
    wgh[side][hh] = iZg * e + (1.0f - gt) * (prev[gi] * (1.0f - rst) + defw[gi] * rst);
  }
  __syncthreads();

  float4 o[8];
  float sacc = 0.0f;
  #pragma unroll
  for (int k = 0; k < 8; ++k) {
    int q4 = q + 32 * k;
    int l = q4 * 4;
    float4 c4 = *(const float4*)&wgp[l];
    float left  = (l == 0)        ? wgh[0][h] : wgp[l - 1];
    float right = (l + 4 == 1024) ? wgh[1][h] : wgp[l + 4];
    // w_s[n] = s0*w_g[n+1] + s1*w_g[n] + s2*w_g[n-1]  (jnp.roll semantics)
    float4 wsv;
    wsv.x = s0 * c4.y   + s1 * c4.x + s2 * left;
    wsv.y = s0 * c4.z   + s1 * c4.y + s2 * c4.x;
    wsv.z = s0 * c4.w   + s1 * c4.z + s2 * c4.y;
    wsv.w = s0 * right  + s1 * c4.w + s2 * c4.z;
    o[k].x = __expf(gamma * __logf(wsv.x + 1e-8f));
    o[k].y = __expf(gamma * __logf(wsv.y + 1e-8f));
    o[k].z = __expf(gamma * __logf(wsv.z + 1e-8f));
    o[k].w = __expf(gamma * __logf(wsv.w + 1e-8f));
    sacc += o[k].x + o[k].y + o[k].z + o[k].w;
  }
  __syncthreads();   // all conv reads complete before in-place overwrite
  #pragma unroll
  for (int k = 0; k < 8; ++k) *(float4*)&wgp[(q + 32 * k) * 4] = o[k];
  sacc += __shfl_xor(sacc, 1, 64);
  sacc += __shfl_xor(sacc, 2, 64);
  sacc += __shfl_xor(sacc, 4, 64);
  sacc += __shfl_xor(sacc, 8, 64);
  sacc += __shfl_xor(sacc, 16, 64);
  if ((t & 31) == 0) atomicAdd(&S[b * 8 + h], sacc);
  grid_barrier(&bar[1], 512u);

  // ---------------- Phase C: normalize + new_w, coef, read ----------------
  if (t < 8) {
    float s = __hip_atomic_load(&S[b * 8 + t], __ATOMIC_RELAXED, __HIP_MEMORY_SCOPE_AGENT);
    invS_s[t] = 1.0f / s;
    kh_s[t] = merge_w[t] / s;
  }
  __syncthreads();

  float invS = invS_s[h];
  float4* nw4 = (float4*)(neww + gbase);
  #pragma unroll
  for (int k = 0; k < 8; ++k) {
    int q4 = q + 32 * k;
    float4 v = *(const float4*)&wgp[q4 * 4];
    float4 on;
    on.x = v.x * invS; on.y = v.y * invS; on.z = v.z * invS; on.w = v.w * invS;
    nw4[q4] = on;
  }
  // merged coef: thread t owns rows 4t..4t+3
  {
    float4 cf = make_float4(0.0f, 0.0f, 0.0f, 0.0f);
    #pragma unroll
    for (int hh = 0; hh < 8; ++hh) {
      float4 v = *(const float4*)&e_s[hh * ESTRIDE + t * 4];
      float k = kh_s[hh];
      cf.x = fmaf(k, v.x, cf.x);
      cf.y = fmaf(k, v.y, cf.y);
      cf.z = fmaf(k, v.z, cf.z);
      cf.w = fmaf(k, v.w, cf.w);
    }
    *(float4*)&coef_s[t * 4] = cf;
  }
  __syncthreads();

  // read pass: out[b,:] += sum_n coef[n] * mem[b,n,:]
  int w4 = t & 31, rg = t >> 5;
  float4 acc2 = make_float4(0.0f, 0.0f, 0.0f, 0.0f);
  #pragma unroll 4
  for (int it = 0; it < 128; ++it) {
    int nl = it * 8 + rg;
    float cf = coef_s[nl];
    float4 mv = m4[(size_t)(n0 + nl) * 32 + w4];
    acc2.x = fmaf(cf, mv.x, acc2.x);
    acc2.y = fmaf(cf, mv.y, acc2.y);
    acc2.z = fmaf(cf, mv.z, acc2.z);
    acc2.w = fmaf(cf, mv.w, acc2.w);
  }
  red4[t] = acc2;
  __syncthreads();
  if (t < 32) {
    float4 s = red4[t];
    #pragma unroll
    for (int j = 1; j < 8; ++j) {
      float4 ov = red4[t + 32 * j];
      s.x += ov.x; s.y += ov.y; s.z += ov.z; s.w += ov.w;
    }
    atomicAdd(&out[b * MWw + t * 4 + 0], s.x);
    atomicAdd(&out[b * MWw + t * 4 + 1], s.y);
    atomicAdd(&out[b * MWw + t * 4 + 2], s.z);
    atomicAdd(&out[b * MWw + t * 4 + 3], s.w);
  }
}

extern "C" void kernel_launch(void* const* d_in, const int* in_sizes, int n_in,
                              void* d_out, int out_size, void* d_ws, size_t ws_size,
                              hipStream_t stream)
{
  const float* cs      = (const float*)d_in[0];
  const float* mem     = (const float*)d_in[1];
  const float* prev    = (const float*)d_in[2];
  const float* defw    = (const float*)d_in[3];
  const float* W_head  = (const float*)d_in[4];
  const float* b_head  = (const float*)d_in[5];
  const float* W_reset = (const float*)d_in[6];
  const float* b_reset = (const float*)d_in[7];
  const float* W_key   = (const float*)d_in[8];
  const float* b_key   = (const float*)d_in[9];
  const float* W_beta  = (const float*)d_in[10];
  const float* b_beta  = (const float*)d_in[11];
  const float* W_gate  = (const float*)d_in[12];
  const float* b_gate  = (const float*)d_in[13];
  const float* W_shift = (const float*)d_in[14];
  const float* b_shift = (const float*)d_in[15];
  const float* W_gamma = (const float*)d_in[16];
  const float* b_gamma = (const float*)d_in[17];
  const float* merge_w = (const float*)d_in[18];

  float* out  = (float*)d_out;          // [B,MW]
  float* neww = out + Bb * MWw;         // [B,H,N] — final new_w

  float* ws_f   = (float*)d_ws;
  float* key_ws = ws_f;                     // 65536 floats
  float* params = ws_f + 65536;             // 4096
  float* Zacc   = ws_f + 69632;             // 512
  float* Sacc   = ws_f + 70144;             // 512 (contiguous with Zacc)
  unsigned* bar = (unsigned*)(ws_f + 70656);// 16 slots (2 used)
  float* ehalo  = ws_f + 70672;             // 8192 (e halos [b][c][2][8])

  k_params<<<dim3(Bb * Hh), dim3(1024), 0, stream>>>(
      cs, W_head, b_head, W_reset, b_reset, W_key, b_key, W_beta, b_beta,
      W_gate, b_gate, W_shift, b_shift, W_gamma, b_gamma, key_ws, params,
      Zacc, out);

  k_fused<<<dim3(8, Bb), dim3(256), 0, stream>>>(
      mem, key_ws, params, prev, defw, merge_w, Zacc, Sacc, ehalo, bar,
      neww, out);
}